// Round 1
// 387.179 us; speedup vs baseline: 1.0128x; 1.0128x over previous
//
#include <hip/hip_runtime.h>
#include <hip/hip_fp16.h>

#define D 128
#define NB 512      // buckets
#define BCAP 4096   // max edges per bucket region (mean 3125, +4.9 sigma ~3400)
#define CHA 4096    // edges per block, pass A

typedef _Float16 half8 __attribute__((ext_vector_type(8)));
typedef float floatx16 __attribute__((ext_vector_type(16)));

__device__ inline float2 h2f(unsigned int u) {
  __half2 h = *(__half2*)&u;
  return __half22float2(h);
}

// ---------------- hx = fp16(emb[x]) ----------------
__global__ void cast_kernel(const float* __restrict__ emb, const int* __restrict__ x,
                            __half* __restrict__ hx, int N) {
  int w = (int)((blockIdx.x * (unsigned)blockDim.x + threadIdx.x) >> 6);
  int lane = threadIdx.x & 63;
  if (w >= N) return;
  int xi = x[w];
  float2 v = ((const float2*)(emb + (size_t)xi * D))[lane];
  ((__half2*)(hx + (size_t)w * D))[lane] = __floats2half2_rn(v.x, v.y);
}

// ---------------- Pass A: bin edges into 512 bucket regions ----------------
__global__ __launch_bounds__(256) void binA_kernel(
    const int* __restrict__ src, const int* __restrict__ dst,
    uint2* __restrict__ binned, int* __restrict__ gcur, int E, int N) {
  __shared__ int hist[NB];
  __shared__ int offs[NB];
  __shared__ int gbs[NB];
  __shared__ int psum[256];
  __shared__ uint2 ebuf[CHA];
  int tid = threadIdx.x;
  int base = blockIdx.x * CHA;

  hist[tid] = 0; hist[tid + 256] = 0;
  __syncthreads();

  int s[16], d[16], pos[16];
#pragma unroll
  for (int j = 0; j < 16; j++) {
    int e = base + j * 256 + tid;  // coalesced
    if (e < E) {
      d[j] = dst[e]; s[j] = src[e];
      int b = (int)((long long)d[j] * NB / N);
      pos[j] = atomicAdd(&hist[b], 1);
    } else d[j] = -1;
  }
  __syncthreads();

  // exclusive scan of hist[512] with 256 threads (2 bins/thread)
  int h0 = hist[2 * tid], h1 = hist[2 * tid + 1];
  int pair = h0 + h1;
  psum[tid] = pair;
  __syncthreads();
  for (int o = 1; o < 256; o <<= 1) {
    int t = (tid >= o) ? psum[tid - o] : 0;
    __syncthreads();
    psum[tid] += t;
    __syncthreads();
  }
  int excl = psum[tid] - pair;
  offs[2 * tid] = excl;
  offs[2 * tid + 1] = excl + h0;
  // reserve global space in this bucket's fixed region
  int rb0 = (h0 > 0) ? atomicAdd(&gcur[2 * tid], h0) : 0;
  int rb1 = (h1 > 0) ? atomicAdd(&gcur[2 * tid + 1], h1) : 0;
  gbs[2 * tid] = 2 * tid * BCAP + rb0;
  gbs[2 * tid + 1] = (2 * tid + 1) * BCAP + rb1;
  __syncthreads();

  // regroup in LDS
#pragma unroll
  for (int j = 0; j < 16; j++) {
    if (d[j] >= 0) {
      int b = (int)((long long)d[j] * NB / N);
      ebuf[offs[b] + pos[j]] = make_uint2((unsigned)s[j], (unsigned)d[j]);
    }
  }
  __syncthreads();

  // write out grouped (per-bucket coalesced bursts)
  int nval = min(CHA, E - base);
  for (int i = tid; i < nval; i += 256) {
    uint2 ed = ebuf[i];
    int b = (int)((long long)(int)ed.y * NB / N);
    binned[gbs[b] + (i - offs[b])] = ed;
  }
}

// ---------------- Pass B: per-bucket CSR build (rowptr + csr), no global atomics --
__global__ __launch_bounds__(256) void binB_kernel(
    const uint2* __restrict__ binned, const int* __restrict__ gcur,
    int* __restrict__ rowptr, int* __restrict__ csr, int E, int N) {
  __shared__ uint2 ebuf[BCAP];   // 32 KB
  __shared__ int lrow[256];
  __shared__ int lcur[256];
  __shared__ int red[256];
  int b = blockIdx.x, tid = threadIdx.x;

  // ebase = sum of gcur[0..b)
  int acc = 0;
  for (int i = tid; i < b; i += 256) acc += gcur[i];
  red[tid] = acc;
  __syncthreads();
  for (int s2 = 128; s2 > 0; s2 >>= 1) {
    if (tid < s2) red[tid] += red[tid + s2];
    __syncthreads();
  }
  int ebase = red[0];
  int cntb = gcur[b];
  int nlo = (int)(((long long)b * N + NB - 1) / NB);
  int nhi = (int)(((long long)(b + 1) * N + NB - 1) / NB);
  int nn = nhi - nlo;
  __syncthreads();

  // stage edges + count
  lcur[tid] = 0;
  __syncthreads();
  for (int i = tid; i < cntb; i += 256) {
    uint2 ed = binned[(size_t)b * BCAP + i];
    ebuf[i] = ed;
    atomicAdd(&lcur[(int)ed.y - nlo], 1);
  }
  __syncthreads();

  // exclusive scan of counts
  int c = lcur[tid];
  red[tid] = c;
  __syncthreads();
  for (int o = 1; o < 256; o <<= 1) {
    int t = (tid >= o) ? red[tid - o] : 0;
    __syncthreads();
    red[tid] += t;
    __syncthreads();
  }
  lrow[tid] = red[tid] - c;
  lcur[tid] = 0;
  __syncthreads();

  // rowptr (coalesced) + placement (writes land in ~13 KB L2 window)
  if (tid < nn) rowptr[nlo + tid] = ebase + lrow[tid];
  if (b == NB - 1 && tid == 0) rowptr[N] = E;
  for (int i = tid; i < cntb; i += 256) {
    uint2 ed = ebuf[i];
    int dl = (int)ed.y - nlo;
    int pos = lrow[dl] + atomicAdd(&lcur[dl], 1);
    csr[ebase + pos] = (int)ed.x;
  }
}

// ---------------- mean aggregation ----------------
// One wave per node. Lane group g (16 lanes) covers one src row per vmem
// instruction via uint4 (16 B/lane x 16 lanes = 256 B row) -> 4 rows fetched
// per instruction per wave (4x fewer VMEM issues than the 4 B/lane version),
// same 4 KB in flight per 16-src batch. Cross-group shfl reduce at the end.
__device__ inline void acc8(uint4 r, float2& a0, float2& a1, float2& a2, float2& a3) {
  float2 f0 = h2f(r.x), f1 = h2f(r.y), f2 = h2f(r.z), f3 = h2f(r.w);
  a0.x += f0.x; a0.y += f0.y;
  a1.x += f1.x; a1.y += f1.y;
  a2.x += f2.x; a2.y += f2.y;
  a3.x += f3.x; a3.y += f3.y;
}

__global__ void agg_kernel(const __half* __restrict__ hh, const int* __restrict__ rowptr,
                           const int* __restrict__ csr, __half* __restrict__ mh, int N) {
  int node = (int)((blockIdx.x * (unsigned)blockDim.x + threadIdx.x) >> 6);
  int lane = threadIdx.x & 63;
  if (node >= N) return;
  int beg = rowptr[node], end = rowptr[node + 1];
  int g = lane >> 4;     // row group 0..3
  int sub = lane & 15;   // uint4 index within the 256 B row
  const uint4* h4 = (const uint4*)hh;
  float2 a0 = make_float2(0.f, 0.f), a1 = make_float2(0.f, 0.f);
  float2 a2 = make_float2(0.f, 0.f), a3 = make_float2(0.f, 0.f);

  int e = beg;
  for (; e + 16 <= end; e += 16) {
    int s0 = csr[e + g];
    int s1 = csr[e + 4 + g];
    int s2 = csr[e + 8 + g];
    int s3 = csr[e + 12 + g];
    uint4 r0 = h4[(size_t)s0 * 16 + sub];
    uint4 r1 = h4[(size_t)s1 * 16 + sub];
    uint4 r2 = h4[(size_t)s2 * 16 + sub];
    uint4 r3 = h4[(size_t)s3 * 16 + sub];
    acc8(r0, a0, a1, a2, a3);
    acc8(r1, a0, a1, a2, a3);
    acc8(r2, a0, a1, a2, a3);
    acc8(r3, a0, a1, a2, a3);
  }
  for (; e + 4 <= end; e += 4) {
    int s = csr[e + g];
    uint4 r = h4[(size_t)s * 16 + sub];
    acc8(r, a0, a1, a2, a3);
  }
  int rem = end - e;
  if (g < rem) {
    int s = csr[e + g];
    uint4 r = h4[(size_t)s * 16 + sub];
    acc8(r, a0, a1, a2, a3);
  }

  // reduce across the 4 row-groups (lanes l, l^16, l^32, l^48)
#pragma unroll
  for (int off = 16; off <= 32; off <<= 1) {
    a0.x += __shfl_xor(a0.x, off); a0.y += __shfl_xor(a0.y, off);
    a1.x += __shfl_xor(a1.x, off); a1.y += __shfl_xor(a1.y, off);
    a2.x += __shfl_xor(a2.x, off); a2.y += __shfl_xor(a2.y, off);
    a3.x += __shfl_xor(a3.x, off); a3.y += __shfl_xor(a3.y, off);
  }

  float inv = 1.0f / fmaxf((float)(end - beg), 1.0f);
  if (g == 0) {
    __half2 o0 = __floats2half2_rn(a0.x * inv, a0.y * inv);
    __half2 o1 = __floats2half2_rn(a1.x * inv, a1.y * inv);
    __half2 o2 = __floats2half2_rn(a2.x * inv, a2.y * inv);
    __half2 o3 = __floats2half2_rn(a3.x * inv, a3.y * inv);
    uint4 o = make_uint4(*(unsigned*)&o0, *(unsigned*)&o1, *(unsigned*)&o2, *(unsigned*)&o3);
    ((uint4*)mh)[(size_t)node * 16 + sub] = o;
  }
}

// ---------------- pack both layers' W into B-fragment order (one launch) ---------
__global__ void packW2_kernel(const float* __restrict__ Wl0, const float* __restrict__ Wr0,
                              const float* __restrict__ Wl1, const float* __restrict__ Wr1,
                              uint4* __restrict__ gW0, uint4* __restrict__ gW1) {
  int gid = blockIdx.x * blockDim.x + threadIdx.x;
  if (gid >= 8192) return;
  int which = gid >> 12;
  int g = gid & 4095;
  const float* Wl = which ? Wl1 : Wl0;
  const float* Wr = which ? Wr1 : Wr0;
  uint4* gW = which ? gW1 : gW0;
  int lane = g & 63;
  int k0 = (g >> 6) & 15;
  int t = g >> 10;
  int n = t * 32 + (lane & 31);
  int kk = k0 * 16 + (lane >> 5) * 8;
  const float* srcp = (kk < D) ? (Wl + (size_t)n * D + kk) : (Wr + (size_t)n * D + (kk - D));
  float4 f0 = *(const float4*)(srcp);
  float4 f1 = *(const float4*)(srcp + 4);
  __half h[8];
  h[0] = __float2half_rn(f0.x); h[1] = __float2half_rn(f0.y);
  h[2] = __float2half_rn(f0.z); h[3] = __float2half_rn(f0.w);
  h[4] = __float2half_rn(f1.x); h[5] = __float2half_rn(f1.y);
  h[6] = __float2half_rn(f1.z); h[7] = __float2half_rn(f1.w);
  gW[g] = *(uint4*)h;
}

// ---------------- MFMA GEMM: out = fp16(relu([mean|h] @ B + bias)) ----------------
#define OS_PITCH 136

__global__ __launch_bounds__(256) void mfma_gemm_kernel(
    const __half* __restrict__ mh, const __half* __restrict__ hsrc,
    const uint4* __restrict__ gWsw, const float* __restrict__ bias,
    __half* __restrict__ out, int N) {
  __shared__ uint4 lds[4096];  // 64 KB
  int tid = threadIdx.x;
  int wave = tid >> 6, lane = tid & 63;
  int row0 = blockIdx.x * 128;

#pragma unroll
  for (int i = 0; i < 16; i++) lds[i * 256 + tid] = gWsw[i * 256 + tid];
  __syncthreads();

  int mrow = row0 + wave * 32 + (lane & 31);
  int koff = (lane >> 5) * 8;
  bool valid = mrow < N;
  const __half* mrp = mh + (size_t)mrow * D + koff;
  const __half* hrp = hsrc + (size_t)mrow * D + koff;

  floatx16 acc[4];
#pragma unroll
  for (int t = 0; t < 4; t++)
#pragma unroll
    for (int i = 0; i < 16; i++) acc[t][i] = 0.f;

  uint4 areg[8];
#pragma unroll
  for (int k0 = 0; k0 < 8; k0++) {
    areg[k0] = valid ? *(const uint4*)(mrp + k0 * 16) : make_uint4(0u, 0u, 0u, 0u);
  }
#pragma unroll
  for (int k0 = 0; k0 < 8; k0++) {
    half8 af = *(half8*)&areg[k0];
#pragma unroll
    for (int t = 0; t < 4; t++) {
      half8 bf = *(half8*)&lds[(t * 16 + k0) * 64 + lane];
      acc[t] = __builtin_amdgcn_mfma_f32_32x32x16_f16(af, bf, acc[t], 0, 0, 0);
    }
  }
#pragma unroll
  for (int k0 = 0; k0 < 8; k0++) {
    areg[k0] = valid ? *(const uint4*)(hrp + k0 * 16) : make_uint4(0u, 0u, 0u, 0u);
  }
#pragma unroll
  for (int k0 = 8; k0 < 16; k0++) {
    half8 af = *(half8*)&areg[k0 - 8];
#pragma unroll
    for (int t = 0; t < 4; t++) {
      half8 bf = *(half8*)&lds[(t * 16 + k0) * 64 + lane];
      acc[t] = __builtin_amdgcn_mfma_f32_32x32x16_f16(af, bf, acc[t], 0, 0, 0);
    }
  }

  __syncthreads();
  __half* Os = (__half*)lds;
  int col = lane & 31;
  int rsub = 4 * (lane >> 5);
#pragma unroll
  for (int t = 0; t < 4; t++) {
    float bv = bias[t * 32 + col];
#pragma unroll
    for (int r = 0; r < 16; r++) {
      int row = (r & 3) + 8 * (r >> 2) + rsub;
      float v = fmaxf(acc[t][r] + bv, 0.f);
      Os[(size_t)(wave * 32 + row) * OS_PITCH + t * 32 + col] = __float2half_rn(v);
    }
  }
  __syncthreads();
#pragma unroll
  for (int i = 0; i < 8; i++) {
    int idx = i * 256 + tid;
    int row = idx >> 4;
    int c16 = idx & 15;
    int grow = row0 + row;
    if (grow < N) {
      uint4 v = *(uint4*)(Os + (size_t)row * OS_PITCH + c16 * 8);
      *(uint4*)(out + (size_t)grow * D + c16 * 8) = v;
    }
  }
}

// ---------------- pair dot: 16 lanes/pair, 4 pairs/quarter unrolled ----------------
__global__ void pairdot_kernel(const __half* __restrict__ h, const int2* __restrict__ pairs,
                               float* __restrict__ out, int P) {
  int wid = (int)((blockIdx.x * (unsigned)blockDim.x + threadIdx.x) >> 6);
  int lane = threadIdx.x & 63;
  int q = lane >> 4;
  int sub = lane & 15;
  int base = wid * 16;

  int p[4];
  int2 pr[4];
#pragma unroll
  for (int j = 0; j < 4; j++) {
    p[j] = base + j * 4 + q;
    pr[j] = (p[j] < P) ? pairs[p[j]] : make_int2(0, 0);
  }
  uint4 ur[4], vr[4];
#pragma unroll
  for (int j = 0; j < 4; j++) {
    ur[j] = *(const uint4*)(h + (size_t)pr[j].x * D + sub * 8);
    vr[j] = *(const uint4*)(h + (size_t)pr[j].y * D + sub * 8);
  }
#pragma unroll
  for (int j = 0; j < 4; j++) {
    float2 a0 = h2f(ur[j].x), a1 = h2f(ur[j].y), a2 = h2f(ur[j].z), a3 = h2f(ur[j].w);
    float2 b0 = h2f(vr[j].x), b1 = h2f(vr[j].y), b2 = h2f(vr[j].z), b3 = h2f(vr[j].w);
    float s = a0.x * b0.x + a0.y * b0.y + a1.x * b1.x + a1.y * b1.y +
              a2.x * b2.x + a2.y * b2.y + a3.x * b3.x + a3.y * b3.y;
#pragma unroll
    for (int off = 1; off <= 8; off <<= 1) s += __shfl_xor(s, off);
    if (sub == 0 && p[j] < P) out[p[j]] = s;
  }
}

// ---------------- launcher ----------------
extern "C" void kernel_launch(void* const* d_in, const int* in_sizes, int n_in,
                              void* d_out, int out_size, void* d_ws, size_t ws_size,
                              hipStream_t stream) {
  const int*   x     = (const int*)d_in[0];
  const int*   eidx  = (const int*)d_in[1];
  const int*   pairs = (const int*)d_in[2];
  const float* emb   = (const float*)d_in[3];
  const float* Wl0   = (const float*)d_in[4];
  const float* bl0   = (const float*)d_in[5];
  const float* Wr0   = (const float*)d_in[6];
  const float* Wl1   = (const float*)d_in[7];
  const float* bl1   = (const float*)d_in[8];
  const float* Wr1   = (const float*)d_in[9];

  const int N = in_sizes[0];
  const int E = in_sizes[1] / 2;
  const int P = in_sizes[2] / 2;
  const int* src = eidx;
  const int* dst = eidx + E;

  char* ws = (char*)d_ws;
  size_t off = 0;
  __half* hx  = (__half*)(ws + off); off += (size_t)N * D * sizeof(__half);
  __half* mh  = (__half*)(ws + off); off += (size_t)N * D * sizeof(__half);
  int* rowptr = (int*)(ws + off);    off += ((size_t)N + 64) * sizeof(int);
  int* gcur   = (int*)(ws + off);    off += 4096;
  uint4* gW0  = (uint4*)(ws + off);  off += 65536;
  uint4* gW1  = (uint4*)(ws + off);  off += 65536;
  uint2* binned = (uint2*)(ws + off); off += (size_t)NB * BCAP * sizeof(uint2);
  int* csr    = (int*)(ws + off);    off += (size_t)E * sizeof(int);
  (void)ws_size; (void)n_in; (void)out_size;

  hipMemsetAsync(gcur, 0, NB * sizeof(int), stream);

  int nbC = (N + 3) / 4;
  int nbA = (E + CHA - 1) / CHA;
  int nbG = (N + 127) / 128;

  cast_kernel<<<nbC, 256, 0, stream>>>(emb, x, hx, N);
  binA_kernel<<<nbA, 256, 0, stream>>>(src, dst, binned, gcur, E, N);
  binB_kernel<<<NB, 256, 0, stream>>>(binned, gcur, rowptr, csr, E, N);

  packW2_kernel<<<32, 256, 0, stream>>>(Wl0, Wr0, Wl1, Wr1, gW0, gW1);

  agg_kernel<<<nbC, 256, 0, stream>>>(hx, rowptr, csr, mh, N);
  mfma_gemm_kernel<<<nbG, 256, 0, stream>>>(mh, hx, gW0, bl0, hx, N);
  agg_kernel<<<nbC, 256, 0, stream>>>(hx, rowptr, csr, mh, N);
  mfma_gemm_kernel<<<nbG, 256, 0, stream>>>(mh, hx, gW1, bl1, hx, N);

  int nbP = (P + 63) / 64;
  pairdot_kernel<<<nbP, 256, 0, stream>>>(hx, (const int2*)pairs, (float*)d_out, P);
}